// Round 4
// baseline (234.695 us; speedup 1.0000x reference)
//
#include <hip/hip_runtime.h>
#include <cstddef>
#include <cstdint>

#define Mq   2048      // B*P
#define Lq   30
#define N1q  1024      // FH
#define N2q  512       // FH/2
#define K1q  1536      // 2*H
#define Hq   768
#define NBLK 512       // loss blocks
#define Z1   4         // gemm1 split-K
#define Z2   8         // gemm2 split-K

typedef float    f32x4 __attribute__((ext_vector_type(4)));
typedef _Float16 f16x8 __attribute__((ext_vector_type(8)));

#define GLD16(gptr, lptr) \
  __builtin_amdgcn_global_load_lds((const __attribute__((address_space(1))) void*)(gptr), \
                                   (__attribute__((address_space(3))) void*)(lptr), 16, 0, 0)

// ---------- prep_all: [0,256) gather->A1 fp16; [256,640) W1T; [640,768) W2T;
//            block 0 also zeros the loss sync counter.
__device__ void transpose_tile(const float* __restrict__ src,
                               _Float16* __restrict__ dst,
                               int K, int N, int k0, int n0) {
  __shared__ float T[64][65];
  const int t = threadIdx.x;
  {
    const int kl = t >> 2, nc = (t & 3) * 16;
    const float* s = src + (size_t)(k0 + kl) * N + n0 + nc;
    float4 v0 = *(const float4*)s;
    float4 v1 = *(const float4*)(s + 4);
    float4 v2 = *(const float4*)(s + 8);
    float4 v3 = *(const float4*)(s + 12);
    T[nc + 0][kl] = v0.x; T[nc + 1][kl] = v0.y; T[nc + 2][kl] = v0.z; T[nc + 3][kl] = v0.w;
    T[nc + 4][kl] = v1.x; T[nc + 5][kl] = v1.y; T[nc + 6][kl] = v1.z; T[nc + 7][kl] = v1.w;
    T[nc + 8][kl] = v2.x; T[nc + 9][kl] = v2.y; T[nc +10][kl] = v2.z; T[nc +11][kl] = v2.w;
    T[nc +12][kl] = v3.x; T[nc +13][kl] = v3.y; T[nc +14][kl] = v3.z; T[nc +15][kl] = v3.w;
  }
  __syncthreads();
  {
    const int nl = t >> 2, kc = (t & 3) * 16;
    __align__(16) _Float16 tmp[16];
    #pragma unroll
    for (int i = 0; i < 16; ++i) tmp[i] = (_Float16)T[nl][kc + i];
    _Float16* d = dst + (size_t)(n0 + nl) * K + k0 + kc;
    *(uint4*)d       = *(const uint4*)tmp;
    *(uint4*)(d + 8) = *(const uint4*)(tmp + 8);
  }
}

__global__ __launch_bounds__(256)
void prep_all(const float* __restrict__ tok, const float* __restrict__ pool,
              const int* __restrict__ npos, const float* __restrict__ W1,
              const float* __restrict__ W2, _Float16* __restrict__ A1,
              _Float16* __restrict__ W1T, _Float16* __restrict__ W2T,
              int* __restrict__ counter) {
  const int bid = blockIdx.x, tid = threadIdx.x;
  if (bid == 0 && tid == 0) *counter = 0;
  if (bid < 256) {
    // gather: 8 rows per block, 32 lanes per row
    const int q = tid >> 5, l32 = tid & 31;
    const int m = bid * 8 + q;
    const int bI = m >> 5, p = m & 31;
    const int pos = npos[bI * 32 + p];
    const float* src1 = tok + ((size_t)bI * 512 + pos) * Hq;
    const float* src2 = pool + (size_t)bI * Hq;
    _Float16* dst = A1 + (size_t)m * K1q;
    for (int g = l32; g < 384; g += 32) {
      const float* s = (g < 192) ? (src1 + g * 4) : (src2 + (g - 192) * 4);
      float4 v = *(const float4*)s;
      __align__(8) _Float16 o[4] = {(_Float16)v.x, (_Float16)v.y, (_Float16)v.z, (_Float16)v.w};
      *(uint2*)(dst + g * 4) = *(const uint2*)o;
    }
  } else if (bid < 640) {
    const int idx = bid - 256;               // 16 n-tiles x 24 k-tiles
    transpose_tile(W1, W1T, K1q, N1q, (idx / 16) * 64, (idx % 16) * 64);
  } else {
    const int idx = bid - 640;               // 8 n-tiles x 16 k-tiles
    transpose_tile(W2, W2T, N1q, N2q, (idx / 8) * 64, (idx % 8) * 64);
  }
}

// ---------- MFMA GEMM: A f16 [Mq][KFULL] @ BT f16 [NC][KFULL] -> fp32 partials
// 128x128 tile, BK=32, 4 waves (2x2 of 64x64), operand-swapped MFMA so the
// accumulator regs map to 4 consecutive COLUMNS -> dwordx4 epilogue stores.
template<int KFULL, int KSLICE, int NC>
__global__ __launch_bounds__(256)
void gemm_f16(const _Float16* __restrict__ A, const _Float16* __restrict__ BT,
              float* __restrict__ Cpart) {
  __shared__ _Float16 As[128 * 32];
  __shared__ _Float16 Bs[128 * 32];
  const int tid = threadIdx.x, w = tid >> 6, lane = tid & 63;
  const int n0 = blockIdx.x * 128, m0 = blockIdx.y * 128, z = blockIdx.z;
  const int ml = lane & 15, g4 = lane >> 4;
  const int wm = (w >> 1) * 64, wn = (w & 1) * 64;

  f32x4 acc[4][4];
  #pragma unroll
  for (int i = 0; i < 4; ++i)
    #pragma unroll
    for (int j = 0; j < 4; ++j)
      #pragma unroll
      for (int r = 0; r < 4; ++r) acc[i][j][r] = 0.f;

  const int rs0 = w * 32 + (lane >> 2);
  const int cl  = lane & 3;

  for (int it = 0; it < KSLICE / 32; ++it) {
    const int kt = z * KSLICE + it * 32;
    __syncthreads();
    #pragma unroll
    for (int t = 0; t < 2; ++t) {
      const int r  = rs0 + t * 16;
      const int cs = cl ^ ((r >> 1) & 3);
      GLD16(A  + (size_t)(m0 + r) * KFULL + kt + cs * 8, As + (w * 32 + t * 16) * 32);
      GLD16(BT + (size_t)(n0 + r) * KFULL + kt + cs * 8, Bs + (w * 32 + t * 16) * 32);
    }
    __syncthreads();
    f16x8 af[4], bf[4];
    #pragma unroll
    for (int i = 0; i < 4; ++i) {
      const int ar = wm + i * 16 + ml;
      af[i] = *(const f16x8*)(As + ar * 32 + ((g4 ^ ((ar >> 1) & 3)) << 3));
      const int br = wn + i * 16 + ml;
      bf[i] = *(const f16x8*)(Bs + br * 32 + ((g4 ^ ((br >> 1) & 3)) << 3));
    }
    // operand-swapped: acc[i][j] regs r=0..3 hold C[m0+wm+i*16+ml][n0+wn+j*16+g4*4+r]
    #pragma unroll
    for (int i = 0; i < 4; ++i)
      #pragma unroll
      for (int j = 0; j < 4; ++j)
        acc[i][j] = __builtin_amdgcn_mfma_f32_16x16x32_f16(bf[j], af[i], acc[i][j], 0, 0, 0);
  }

  float* Cp = Cpart + (size_t)z * Mq * NC;
  #pragma unroll
  for (int i = 0; i < 4; ++i) {
    const int row = m0 + wm + i * 16 + ml;
    #pragma unroll
    for (int j = 0; j < 4; ++j) {
      const int col = n0 + wn + j * 16 + g4 * 4;
      *(float4*)(Cp + (size_t)row * NC + col) = *(const float4*)&acc[i][j];
    }
  }
}

// ---------- combine1: h1 = f16(sum_z p_z + b1)   [2048][1024]
__global__ __launch_bounds__(256)
void combine1(const float* __restrict__ P, const float* __restrict__ b1,
              _Float16* __restrict__ h1) {
  const int idx = (blockIdx.x * 256 + threadIdx.x) * 4;
  const int col = idx & (N1q - 1);
  const size_t MN = (size_t)Mq * N1q;
  float4 s = *(const float4*)(b1 + col);
  #pragma unroll
  for (int z = 0; z < Z1; ++z) {
    float4 v = *(const float4*)(P + (size_t)z * MN + idx);
    s.x += v.x; s.y += v.y; s.z += v.z; s.w += v.w;
  }
  __align__(8) _Float16 o[4] = {(_Float16)s.x, (_Float16)s.y, (_Float16)s.z, (_Float16)s.w};
  *(uint2*)(h1 + idx) = *(const uint2*)o;
}

// ---------- GEMM3 + fused loss + fused finalize (last-block pattern)
__global__ __launch_bounds__(256)
void loss_kernel(const float* __restrict__ C2, const float* __restrict__ b2,
                 const float* __restrict__ W3, const float* __restrict__ b3,
                 const float* __restrict__ labels, float* __restrict__ part,
                 int* __restrict__ counter, float* __restrict__ out) {
  __shared__ float hrow[4][512];
  __shared__ float red[4][5];
  __shared__ float fred[32][5];
  __shared__ int lastFlag;
  const int tid = threadIdx.x, w = tid >> 6, lane = tid & 63;
  const int m = blockIdx.x * 4 + w;
  const size_t MN2 = (size_t)Mq * N2q;

  // stage h row: h[k] = b2[k] + sum_z C2part[z][m][k]
  {
    const int k = lane * 8;
    float4 s0 = *(const float4*)(b2 + k);
    float4 s1 = *(const float4*)(b2 + k + 4);
    const float* cp = C2 + (size_t)m * N2q + k;
    #pragma unroll
    for (int z = 0; z < Z2; ++z) {
      float4 v0 = *(const float4*)(cp + (size_t)z * MN2);
      float4 v1 = *(const float4*)(cp + (size_t)z * MN2 + 4);
      s0.x += v0.x; s0.y += v0.y; s0.z += v0.z; s0.w += v0.w;
      s1.x += v1.x; s1.y += v1.y; s1.z += v1.z; s1.w += v1.w;
    }
    *(float4*)&hrow[w][k]     = s0;
    *(float4*)&hrow[w][k + 4] = s1;
  }
  __syncthreads();

  const int c  = lane & 31;
  const int kh = lane >> 5;
  float a0 = 0.f, a1 = 0.f, a2 = 0.f, a3 = 0.f;
  if (c < Lq) {
    const float* hp = hrow[w] + kh * 256;
    const float* wp = W3 + (size_t)(kh * 256) * Lq + c;
    #pragma unroll 4
    for (int i = 0; i < 256; i += 4) {
      a0 = fmaf(hp[i],     wp[(i)     * Lq], a0);
      a1 = fmaf(hp[i + 1], wp[(i + 1) * Lq], a1);
      a2 = fmaf(hp[i + 2], wp[(i + 2) * Lq], a2);
      a3 = fmaf(hp[i + 3], wp[(i + 3) * Lq], a3);
    }
  }
  float a = (a0 + a1) + (a2 + a3);
  a += __shfl_xor(a, 32);

  const bool act = lane < Lq;
  float logit = 0.f, lab = 0.f;
  if (act) {
    logit = a + b3[lane];
    lab = labels[(size_t)m * Lq + lane];
  }

  const unsigned long long validmask = __ballot(act && lab != -1.0f);
  const unsigned long long outmask   = __ballot(act && logit > 0.0f);
  const unsigned long long labmask   = __ballot(act && lab == 1.0f);
  const bool valid = (validmask != 0ULL);
  const int count_out = __popcll(outmask);
  const int count_lab = __popcll(labmask);

  float bce = 0.f;
  if (act && valid) {
    const float x = logit;
    bce = fmaxf(x, 0.f) + log1pf(expf(-fabsf(x))) - x * lab;
  }
  bce += __shfl_xor(bce, 16); bce += __shfl_xor(bce, 8);
  bce += __shfl_xor(bce, 4);  bce += __shfl_xor(bce, 2);
  bce += __shfl_xor(bce, 1);

  if (lane == 0) {
    float pb = 0.f, pv = 0.f, pc = 0.f, pe = 0.f, pp = 0.f;
    if (valid) {
      pb = bce; pv = 1.f;
      const float d = (float)count_out - (float)count_lab;
      pc = d * d;
    }
    if (count_out == 1 && count_lab == 1) {
      const float po = (float)(__ffsll((long long)outmask) - 1);
      const float pl = (float)(__ffsll((long long)labmask) - 1);
      pe = 1.f;
      const float dp = po - pl;
      pp = dp * dp;
    }
    red[w][0] = pb; red[w][1] = pv; red[w][2] = pc; red[w][3] = pe; red[w][4] = pp;
  }
  __syncthreads();
  if (tid < 5) {
    part[blockIdx.x * 5 + tid] =
        red[0][tid] + red[1][tid] + red[2][tid] + red[3][tid];
  }
  // ---- last-block finalize
  __threadfence();
  if (tid == 0) {
    const int old = atomicAdd(counter, 1);
    lastFlag = (old == (int)gridDim.x - 1);
  }
  __syncthreads();
  if (lastFlag) {
    if (tid < 160) {
      const int j = tid % 5, grp = tid / 5;
      float s = 0.f;
      for (int i = grp; i < NBLK; i += 32) s += part[i * 5 + j];
      fred[grp][j] = s;
    }
    __syncthreads();
    if (tid == 0) {
      float t0 = 0.f, t1 = 0.f, t2 = 0.f, t3 = 0.f, t4 = 0.f;
      #pragma unroll
      for (int g = 0; g < 32; ++g) {
        t0 += fred[g][0]; t1 += fred[g][1]; t2 += fred[g][2];
        t3 += fred[g][3]; t4 += fred[g][4];
      }
      const float bceL = t0 / (t1 * (float)Lq);
      const float cntL = 10.0f * t2 / (float)Mq;
      const float posL = (t3 > 0.f) ? 5.0f * t4 / fmaxf(t3, 1.0f) : 0.f;
      out[0] = bceL + cntL + posL;
    }
  }
}

extern "C" void kernel_launch(void* const* d_in, const int* in_sizes, int n_in,
                              void* d_out, int out_size, void* d_ws, size_t ws_size,
                              hipStream_t stream) {
  const float* tok    = (const float*)d_in[0];
  const float* pool   = (const float*)d_in[1];
  const int*   npos   = (const int*)  d_in[2];
  const float* labels = (const float*)d_in[3];
  const float* W1     = (const float*)d_in[4];
  const float* b1     = (const float*)d_in[5];
  const float* W2     = (const float*)d_in[6];
  const float* b2     = (const float*)d_in[7];
  const float* W3     = (const float*)d_in[8];
  const float* b3     = (const float*)d_in[9];
  float* out = (float*)d_out;

  char* ws = (char*)d_ws;
  // C2p overlays A1+C1p (both dead before gemm2 runs).
  _Float16* A1   = (_Float16*)(ws + 0x00000000);  // 6 MB  [2048][1536]
  float*    C2p  = (float*)   (ws + 0x00000000);  // 32 MB [8][2048][512]
  float*    C1p  = (float*)   (ws + 0x00600000);  // 32 MB [4][2048][1024]
  _Float16* W1T  = (_Float16*)(ws + 0x02600000);  // 3 MB  [1024][1536]
  _Float16* W2T  = (_Float16*)(ws + 0x02A00000);  // 1 MB  [512][1024]
  _Float16* h1   = (_Float16*)(ws + 0x02E00000);  // 4 MB  [2048][1024]
  float*    part = (float*)   (ws + 0x03200000);  // 10 KB [512][5]
  int*      cnt  = (int*)     (ws + 0x03210000);  // 4 B

  prep_all<<<768, 256, 0, stream>>>(tok, pool, npos, W1, W2, A1, W1T, W2T, cnt);
  gemm_f16<K1q, K1q / Z1, N1q><<<dim3(8, 16, Z1), 256, 0, stream>>>(A1, W1T, C1p);
  combine1<<<2048, 256, 0, stream>>>(C1p, b1, h1);
  gemm_f16<N1q, N1q / Z2, N2q><<<dim3(4, 16, Z2), 256, 0, stream>>>(h1, W2T, C2p);
  loss_kernel<<<NBLK, 256, 0, stream>>>(C2p, b2, W3, b3, labels, part, cnt, out);
}

// Round 5
// 204.819 us; speedup vs baseline: 1.1459x; 1.1459x over previous
//
#include <hip/hip_runtime.h>
#include <cstddef>
#include <cstdint>

#define Mq   2048      // B*P
#define Lq   30
#define N1q  1024      // FH
#define N2q  512       // FH/2
#define K1q  1536      // 2*H
#define Hq   768
#define NBLK 512       // loss blocks
#define Z1   2         // gemm1 split-K  (256 blocks = 1/CU; 4 was a net loss)
#define Z2   4         // gemm2 split-K

typedef float    f32x4 __attribute__((ext_vector_type(4)));
typedef _Float16 f16x8 __attribute__((ext_vector_type(8)));

#define GLD16(gptr, lptr) \
  __builtin_amdgcn_global_load_lds((const __attribute__((address_space(1))) void*)(gptr), \
                                   (__attribute__((address_space(3))) void*)(lptr), 16, 0, 0)

// ---------- prep_all: [0,256) gather->A1 fp16; [256,640) W1T; [640,768) W2T
__device__ void transpose_tile(const float* __restrict__ src,
                               _Float16* __restrict__ dst,
                               int K, int N, int k0, int n0) {
  __shared__ float T[64][65];
  const int t = threadIdx.x;
  {
    const int kl = t >> 2, nc = (t & 3) * 16;
    const float* s = src + (size_t)(k0 + kl) * N + n0 + nc;
    float4 v0 = *(const float4*)s;
    float4 v1 = *(const float4*)(s + 4);
    float4 v2 = *(const float4*)(s + 8);
    float4 v3 = *(const float4*)(s + 12);
    T[nc + 0][kl] = v0.x; T[nc + 1][kl] = v0.y; T[nc + 2][kl] = v0.z; T[nc + 3][kl] = v0.w;
    T[nc + 4][kl] = v1.x; T[nc + 5][kl] = v1.y; T[nc + 6][kl] = v1.z; T[nc + 7][kl] = v1.w;
    T[nc + 8][kl] = v2.x; T[nc + 9][kl] = v2.y; T[nc +10][kl] = v2.z; T[nc +11][kl] = v2.w;
    T[nc +12][kl] = v3.x; T[nc +13][kl] = v3.y; T[nc +14][kl] = v3.z; T[nc +15][kl] = v3.w;
  }
  __syncthreads();
  {
    const int nl = t >> 2, kc = (t & 3) * 16;
    __align__(16) _Float16 tmp[16];
    #pragma unroll
    for (int i = 0; i < 16; ++i) tmp[i] = (_Float16)T[nl][kc + i];
    _Float16* d = dst + (size_t)(n0 + nl) * K + k0 + kc;
    *(uint4*)d       = *(const uint4*)tmp;
    *(uint4*)(d + 8) = *(const uint4*)(tmp + 8);
  }
}

__global__ __launch_bounds__(256)
void prep_all(const float* __restrict__ tok, const float* __restrict__ pool,
              const int* __restrict__ npos, const float* __restrict__ W1,
              const float* __restrict__ W2, _Float16* __restrict__ A1,
              _Float16* __restrict__ W1T, _Float16* __restrict__ W2T) {
  const int bid = blockIdx.x, tid = threadIdx.x;
  if (bid < 256) {
    // gather: 8 rows per block, 32 lanes per row
    const int q = tid >> 5, l32 = tid & 31;
    const int m = bid * 8 + q;
    const int bI = m >> 5, p = m & 31;
    const int pos = npos[bI * 32 + p];
    const float* src1 = tok + ((size_t)bI * 512 + pos) * Hq;
    const float* src2 = pool + (size_t)bI * Hq;
    _Float16* dst = A1 + (size_t)m * K1q;
    for (int g = l32; g < 384; g += 32) {
      const float* s = (g < 192) ? (src1 + g * 4) : (src2 + (g - 192) * 4);
      float4 v = *(const float4*)s;
      __align__(8) _Float16 o[4] = {(_Float16)v.x, (_Float16)v.y, (_Float16)v.z, (_Float16)v.w};
      *(uint2*)(dst + g * 4) = *(const uint2*)o;
    }
  } else if (bid < 640) {
    const int idx = bid - 256;               // 16 n-tiles x 24 k-tiles
    transpose_tile(W1, W1T, K1q, N1q, (idx / 16) * 64, (idx % 16) * 64);
  } else {
    const int idx = bid - 640;               // 8 n-tiles x 16 k-tiles
    transpose_tile(W2, W2T, N1q, N2q, (idx / 8) * 64, (idx % 8) * 64);
  }
}

// ---------- MFMA GEMM: A f16 [Mq][KFULL] @ BT f16 [NC][KFULL] -> fp32 partials
// 128x128 tile, BK=32, 4 waves (2x2 of 64x64), operand-swapped MFMA so the
// accumulator regs map to 4 consecutive COLUMNS -> dwordx4 epilogue stores.
template<int KFULL, int KSLICE, int NC>
__global__ __launch_bounds__(256)
void gemm_f16(const _Float16* __restrict__ A, const _Float16* __restrict__ BT,
              float* __restrict__ Cpart) {
  __shared__ _Float16 As[128 * 32];
  __shared__ _Float16 Bs[128 * 32];
  const int tid = threadIdx.x, w = tid >> 6, lane = tid & 63;
  const int n0 = blockIdx.x * 128, m0 = blockIdx.y * 128, z = blockIdx.z;
  const int ml = lane & 15, g4 = lane >> 4;
  const int wm = (w >> 1) * 64, wn = (w & 1) * 64;

  f32x4 acc[4][4];
  #pragma unroll
  for (int i = 0; i < 4; ++i)
    #pragma unroll
    for (int j = 0; j < 4; ++j)
      #pragma unroll
      for (int r = 0; r < 4; ++r) acc[i][j][r] = 0.f;

  const int rs0 = w * 32 + (lane >> 2);
  const int cl  = lane & 3;

  for (int it = 0; it < KSLICE / 32; ++it) {
    const int kt = z * KSLICE + it * 32;
    __syncthreads();
    #pragma unroll
    for (int t = 0; t < 2; ++t) {
      const int r  = rs0 + t * 16;
      const int cs = cl ^ ((r >> 1) & 3);
      GLD16(A  + (size_t)(m0 + r) * KFULL + kt + cs * 8, As + (w * 32 + t * 16) * 32);
      GLD16(BT + (size_t)(n0 + r) * KFULL + kt + cs * 8, Bs + (w * 32 + t * 16) * 32);
    }
    __syncthreads();
    f16x8 af[4], bf[4];
    #pragma unroll
    for (int i = 0; i < 4; ++i) {
      const int ar = wm + i * 16 + ml;
      af[i] = *(const f16x8*)(As + ar * 32 + ((g4 ^ ((ar >> 1) & 3)) << 3));
      const int br = wn + i * 16 + ml;
      bf[i] = *(const f16x8*)(Bs + br * 32 + ((g4 ^ ((br >> 1) & 3)) << 3));
    }
    // operand-swapped: acc[i][j] regs r=0..3 hold C[m0+wm+i*16+ml][n0+wn+j*16+g4*4+r]
    #pragma unroll
    for (int i = 0; i < 4; ++i)
      #pragma unroll
      for (int j = 0; j < 4; ++j)
        acc[i][j] = __builtin_amdgcn_mfma_f32_16x16x32_f16(bf[j], af[i], acc[i][j], 0, 0, 0);
  }

  float* Cp = Cpart + (size_t)z * Mq * NC;
  #pragma unroll
  for (int i = 0; i < 4; ++i) {
    const int row = m0 + wm + i * 16 + ml;
    #pragma unroll
    for (int j = 0; j < 4; ++j) {
      const int col = n0 + wn + j * 16 + g4 * 4;
      *(float4*)(Cp + (size_t)row * NC + col) = *(const float4*)&acc[i][j];
    }
  }
}

// ---------- combine1: h1 = f16(sum_z p_z + b1)   [2048][1024]
__global__ __launch_bounds__(256)
void combine1(const float* __restrict__ P, const float* __restrict__ b1,
              _Float16* __restrict__ h1) {
  const int idx = (blockIdx.x * 256 + threadIdx.x) * 4;
  const int col = idx & (N1q - 1);
  const size_t MN = (size_t)Mq * N1q;
  float4 s = *(const float4*)(b1 + col);
  #pragma unroll
  for (int z = 0; z < Z1; ++z) {
    float4 v = *(const float4*)(P + (size_t)z * MN + idx);
    s.x += v.x; s.y += v.y; s.z += v.z; s.w += v.w;
  }
  __align__(8) _Float16 o[4] = {(_Float16)s.x, (_Float16)s.y, (_Float16)s.z, (_Float16)s.w};
  *(uint2*)(h1 + idx) = *(const uint2*)o;
}

// ---------- GEMM3 + fused loss, atomic-free: one 5-float partial per block
__global__ __launch_bounds__(256)
void loss_kernel(const float* __restrict__ C2, const float* __restrict__ b2,
                 const float* __restrict__ W3, const float* __restrict__ b3,
                 const float* __restrict__ labels, float* __restrict__ part) {
  __shared__ float hrow[4][512];
  __shared__ float red[4][5];
  const int tid = threadIdx.x, w = tid >> 6, lane = tid & 63;
  const int m = blockIdx.x * 4 + w;
  const size_t MN2 = (size_t)Mq * N2q;

  // stage h row: h[k] = b2[k] + sum_z C2part[z][m][k]
  {
    const int k = lane * 8;
    float4 s0 = *(const float4*)(b2 + k);
    float4 s1 = *(const float4*)(b2 + k + 4);
    const float* cp = C2 + (size_t)m * N2q + k;
    #pragma unroll
    for (int z = 0; z < Z2; ++z) {
      float4 v0 = *(const float4*)(cp + (size_t)z * MN2);
      float4 v1 = *(const float4*)(cp + (size_t)z * MN2 + 4);
      s0.x += v0.x; s0.y += v0.y; s0.z += v0.z; s0.w += v0.w;
      s1.x += v1.x; s1.y += v1.y; s1.z += v1.z; s1.w += v1.w;
    }
    *(float4*)&hrow[w][k]     = s0;
    *(float4*)&hrow[w][k + 4] = s1;
  }
  __syncthreads();

  const int c  = lane & 31;
  const int kh = lane >> 5;
  float a0 = 0.f, a1 = 0.f, a2 = 0.f, a3 = 0.f;
  if (c < Lq) {
    const float* hp = hrow[w] + kh * 256;
    const float* wp = W3 + (size_t)(kh * 256) * Lq + c;
    #pragma unroll 4
    for (int i = 0; i < 256; i += 4) {
      a0 = fmaf(hp[i],     wp[(i)     * Lq], a0);
      a1 = fmaf(hp[i + 1], wp[(i + 1) * Lq], a1);
      a2 = fmaf(hp[i + 2], wp[(i + 2) * Lq], a2);
      a3 = fmaf(hp[i + 3], wp[(i + 3) * Lq], a3);
    }
  }
  float a = (a0 + a1) + (a2 + a3);
  a += __shfl_xor(a, 32);   // combine k-halves

  const bool act = lane < Lq;
  float logit = 0.f, lab = 0.f;
  if (act) {
    logit = a + b3[lane];
    lab = labels[(size_t)m * Lq + lane];
  }

  const unsigned long long validmask = __ballot(act && lab != -1.0f);
  const unsigned long long outmask   = __ballot(act && logit > 0.0f);
  const unsigned long long labmask   = __ballot(act && lab == 1.0f);
  const bool valid = (validmask != 0ULL);
  const int count_out = __popcll(outmask);
  const int count_lab = __popcll(labmask);

  float bce = 0.f;
  if (act && valid) {
    const float x = logit;
    bce = fmaxf(x, 0.f) + log1pf(expf(-fabsf(x))) - x * lab;
  }
  bce += __shfl_xor(bce, 16); bce += __shfl_xor(bce, 8);
  bce += __shfl_xor(bce, 4);  bce += __shfl_xor(bce, 2);
  bce += __shfl_xor(bce, 1);

  if (lane == 0) {
    float pb = 0.f, pv = 0.f, pc = 0.f, pe = 0.f, pp = 0.f;
    if (valid) {
      pb = bce; pv = 1.f;
      const float d = (float)count_out - (float)count_lab;
      pc = d * d;
    }
    if (count_out == 1 && count_lab == 1) {
      const float po = (float)(__ffsll((long long)outmask) - 1);
      const float pl = (float)(__ffsll((long long)labmask) - 1);
      pe = 1.f;
      const float dp = po - pl;
      pp = dp * dp;
    }
    red[w][0] = pb; red[w][1] = pv; red[w][2] = pc; red[w][3] = pe; red[w][4] = pp;
  }
  __syncthreads();
  if (tid < 5) {
    part[blockIdx.x * 5 + tid] =
        red[0][tid] + red[1][tid] + red[2][tid] + red[3][tid];
  }
}

// ---------- finalize: sum NBLK 5-float partials -> scalar loss
__global__ __launch_bounds__(256)
void finalize_kernel(const float* __restrict__ part, float* __restrict__ out) {
  __shared__ float red[32][5];
  const int t = threadIdx.x;
  if (t < 160) {
    const int j = t % 5, grp = t / 5;
    float s = 0.f;
    for (int i = grp; i < NBLK; i += 32) s += part[i * 5 + j];
    red[grp][j] = s;
  }
  __syncthreads();
  if (t == 0) {
    float t0 = 0.f, t1 = 0.f, t2 = 0.f, t3 = 0.f, t4 = 0.f;
    #pragma unroll
    for (int g = 0; g < 32; ++g) {
      t0 += red[g][0]; t1 += red[g][1]; t2 += red[g][2];
      t3 += red[g][3]; t4 += red[g][4];
    }
    const float bce = t0 / (t1 * (float)Lq);
    const float cnt = 10.0f * t2 / (float)Mq;
    const float pos = (t3 > 0.f) ? 5.0f * t4 / fmaxf(t3, 1.0f) : 0.f;
    out[0] = bce + cnt + pos;
  }
}

extern "C" void kernel_launch(void* const* d_in, const int* in_sizes, int n_in,
                              void* d_out, int out_size, void* d_ws, size_t ws_size,
                              hipStream_t stream) {
  const float* tok    = (const float*)d_in[0];
  const float* pool   = (const float*)d_in[1];
  const int*   npos   = (const int*)  d_in[2];
  const float* labels = (const float*)d_in[3];
  const float* W1     = (const float*)d_in[4];
  const float* b1     = (const float*)d_in[5];
  const float* W2     = (const float*)d_in[6];
  const float* b2     = (const float*)d_in[7];
  const float* W3     = (const float*)d_in[8];
  const float* b3     = (const float*)d_in[9];
  float* out = (float*)d_out;

  char* ws = (char*)d_ws;
  // C2p overlays A1 (dead once gemm2 starts; gemm2 reads h1/W2T only).
  _Float16* A1   = (_Float16*)(ws + 0x00000000);  // 6 MB  [2048][1536]
  float*    C2p  = (float*)   (ws + 0x00000000);  // 16 MB [4][2048][512]
  float*    C1p  = (float*)   (ws + 0x00600000);  // 16 MB [2][2048][1024]
  _Float16* W1T  = (_Float16*)(ws + 0x01600000);  // 3 MB  [1024][1536]
  _Float16* W2T  = (_Float16*)(ws + 0x01A00000);  // 1 MB  [512][1024]
  _Float16* h1   = (_Float16*)(ws + 0x01B00000);  // 4 MB  [2048][1024]
  float*    part = (float*)   (ws + 0x01F00000);  // 10 KB [512][5]

  prep_all<<<768, 256, 0, stream>>>(tok, pool, npos, W1, W2, A1, W1T, W2T);
  gemm_f16<K1q, K1q / Z1, N1q><<<dim3(8, 16, Z1), 256, 0, stream>>>(A1, W1T, C1p);
  combine1<<<2048, 256, 0, stream>>>(C1p, b1, h1);
  gemm_f16<N1q, N1q / Z2, N2q><<<dim3(4, 16, Z2), 256, 0, stream>>>(h1, W2T, C2p);
  loss_kernel<<<NBLK, 256, 0, stream>>>(C2p, b2, W3, b3, labels, part);
  finalize_kernel<<<1, 256, 0, stream>>>(part, out);
}

// Round 6
// 202.819 us; speedup vs baseline: 1.1572x; 1.0099x over previous
//
#include <hip/hip_runtime.h>
#include <cstddef>
#include <cstdint>

#define Mq   2048      // B*P
#define Lq   30
#define N1q  1024      // FH
#define N2q  512       // FH/2
#define K1q  1536      // 2*H
#define Hq   768
#define NBLK 512       // loss blocks
#define Z1   2         // gemm1 split-K
#define Z2   4         // gemm2 split-K

typedef float    f32x4 __attribute__((ext_vector_type(4)));
typedef _Float16 f16x8 __attribute__((ext_vector_type(8)));

#define GLD16(gptr, lptr) \
  __builtin_amdgcn_global_load_lds((const __attribute__((address_space(1))) void*)(gptr), \
                                   (__attribute__((address_space(3))) void*)(lptr), 16, 0, 0)

// ---------- prep_all: [0,256) gather->A1 fp16; [256,640) W1T; [640,768) W2T
__device__ void transpose_tile(const float* __restrict__ src,
                               _Float16* __restrict__ dst,
                               int K, int N, int k0, int n0) {
  __shared__ float T[64][65];
  const int t = threadIdx.x;
  {
    const int kl = t >> 2, nc = (t & 3) * 16;
    const float* s = src + (size_t)(k0 + kl) * N + n0 + nc;
    float4 v0 = *(const float4*)s;
    float4 v1 = *(const float4*)(s + 4);
    float4 v2 = *(const float4*)(s + 8);
    float4 v3 = *(const float4*)(s + 12);
    T[nc + 0][kl] = v0.x; T[nc + 1][kl] = v0.y; T[nc + 2][kl] = v0.z; T[nc + 3][kl] = v0.w;
    T[nc + 4][kl] = v1.x; T[nc + 5][kl] = v1.y; T[nc + 6][kl] = v1.z; T[nc + 7][kl] = v1.w;
    T[nc + 8][kl] = v2.x; T[nc + 9][kl] = v2.y; T[nc +10][kl] = v2.z; T[nc +11][kl] = v2.w;
    T[nc +12][kl] = v3.x; T[nc +13][kl] = v3.y; T[nc +14][kl] = v3.z; T[nc +15][kl] = v3.w;
  }
  __syncthreads();
  {
    const int nl = t >> 2, kc = (t & 3) * 16;
    __align__(16) _Float16 tmp[16];
    #pragma unroll
    for (int i = 0; i < 16; ++i) tmp[i] = (_Float16)T[nl][kc + i];
    _Float16* d = dst + (size_t)(n0 + nl) * K + k0 + kc;
    *(uint4*)d       = *(const uint4*)tmp;
    *(uint4*)(d + 8) = *(const uint4*)(tmp + 8);
  }
}

__global__ __launch_bounds__(256)
void prep_all(const float* __restrict__ tok, const float* __restrict__ pool,
              const int* __restrict__ npos, const float* __restrict__ W1,
              const float* __restrict__ W2, _Float16* __restrict__ A1,
              _Float16* __restrict__ W1T, _Float16* __restrict__ W2T) {
  const int bid = blockIdx.x, tid = threadIdx.x;
  if (bid < 256) {
    const int q = tid >> 5, l32 = tid & 31;
    const int m = bid * 8 + q;
    const int bI = m >> 5, p = m & 31;
    const int pos = npos[bI * 32 + p];
    const float* src1 = tok + ((size_t)bI * 512 + pos) * Hq;
    const float* src2 = pool + (size_t)bI * Hq;
    _Float16* dst = A1 + (size_t)m * K1q;
    for (int g = l32; g < 384; g += 32) {
      const float* s = (g < 192) ? (src1 + g * 4) : (src2 + (g - 192) * 4);
      float4 v = *(const float4*)s;
      __align__(8) _Float16 o[4] = {(_Float16)v.x, (_Float16)v.y, (_Float16)v.z, (_Float16)v.w};
      *(uint2*)(dst + g * 4) = *(const uint2*)o;
    }
  } else if (bid < 640) {
    const int idx = bid - 256;               // 16 n-tiles x 24 k-tiles
    transpose_tile(W1, W1T, K1q, N1q, (idx / 16) * 64, (idx % 16) * 64);
  } else {
    const int idx = bid - 640;               // 8 n-tiles x 16 k-tiles
    transpose_tile(W2, W2T, N1q, N2q, (idx / 8) * 64, (idx % 8) * 64);
  }
}

// ---------- gemm1: A1 f16 @ W1T f16 -> C1 partials in FP16 (split-K z=Z1)
// 128x128 tile, BK=32, operand-swapped MFMA (acc regs = 4 consecutive cols).
__global__ __launch_bounds__(256)
void gemm1_f16(const _Float16* __restrict__ A, const _Float16* __restrict__ BT,
               _Float16* __restrict__ Cpart) {
  __shared__ _Float16 As[128 * 32];
  __shared__ _Float16 Bs[128 * 32];
  const int tid = threadIdx.x, w = tid >> 6, lane = tid & 63;
  const int n0 = blockIdx.x * 128, m0 = blockIdx.y * 128, z = blockIdx.z;
  const int ml = lane & 15, g4 = lane >> 4;
  const int wm = (w >> 1) * 64, wn = (w & 1) * 64;

  f32x4 acc[4][4];
  #pragma unroll
  for (int i = 0; i < 4; ++i)
    #pragma unroll
    for (int j = 0; j < 4; ++j)
      #pragma unroll
      for (int r = 0; r < 4; ++r) acc[i][j][r] = 0.f;

  const int rs0 = w * 32 + (lane >> 2);
  const int cl  = lane & 3;

  for (int it = 0; it < (K1q / Z1) / 32; ++it) {
    const int kt = z * (K1q / Z1) + it * 32;
    __syncthreads();
    #pragma unroll
    for (int t = 0; t < 2; ++t) {
      const int r  = rs0 + t * 16;
      const int cs = cl ^ ((r >> 1) & 3);
      GLD16(A  + (size_t)(m0 + r) * K1q + kt + cs * 8, As + (w * 32 + t * 16) * 32);
      GLD16(BT + (size_t)(n0 + r) * K1q + kt + cs * 8, Bs + (w * 32 + t * 16) * 32);
    }
    __syncthreads();
    f16x8 af[4], bf[4];
    #pragma unroll
    for (int i = 0; i < 4; ++i) {
      const int ar = wm + i * 16 + ml;
      af[i] = *(const f16x8*)(As + ar * 32 + ((g4 ^ ((ar >> 1) & 3)) << 3));
      const int br = wn + i * 16 + ml;
      bf[i] = *(const f16x8*)(Bs + br * 32 + ((g4 ^ ((br >> 1) & 3)) << 3));
    }
    #pragma unroll
    for (int i = 0; i < 4; ++i)
      #pragma unroll
      for (int j = 0; j < 4; ++j)
        acc[i][j] = __builtin_amdgcn_mfma_f32_16x16x32_f16(bf[j], af[i], acc[i][j], 0, 0, 0);
  }

  _Float16* Cp = Cpart + (size_t)z * Mq * N1q;
  #pragma unroll
  for (int i = 0; i < 4; ++i) {
    const int row = m0 + wm + i * 16 + ml;
    #pragma unroll
    for (int j = 0; j < 4; ++j) {
      const int col = n0 + wn + j * 16 + g4 * 4;
      __align__(8) _Float16 o[4] = {(_Float16)acc[i][j][0], (_Float16)acc[i][j][1],
                                    (_Float16)acc[i][j][2], (_Float16)acc[i][j][3]};
      *(uint2*)(Cp + (size_t)row * N1q + col) = *(const uint2*)o;
    }
  }
}

// ---------- gemm2 fused: A = f16(sum of 2 fp16 C1 partials + b1) staged in LDS,
// B = W2T via global_load_lds. Output: C2 fp32 partials (split-K z=Z2).
__global__ __launch_bounds__(256)
void gemm2_fused(const _Float16* __restrict__ C1, const float* __restrict__ b1,
                 const _Float16* __restrict__ BT, float* __restrict__ Cpart) {
  __shared__ _Float16 As[128 * 32];
  __shared__ _Float16 Bs[128 * 32];
  const int tid = threadIdx.x, w = tid >> 6, lane = tid & 63;
  const int n0 = blockIdx.x * 128, m0 = blockIdx.y * 128, z = blockIdx.z;
  const int ml = lane & 15, g4 = lane >> 4;
  const int wm = (w >> 1) * 64, wn = (w & 1) * 64;
  const size_t MN1 = (size_t)Mq * N1q;      // fp16 partial stride

  f32x4 acc[4][4];
  #pragma unroll
  for (int i = 0; i < 4; ++i)
    #pragma unroll
    for (int j = 0; j < 4; ++j)
      #pragma unroll
      for (int r = 0; r < 4; ++r) acc[i][j][r] = 0.f;

  const int rs0 = w * 32 + (lane >> 2);
  const int cl  = lane & 3;
  const int r2  = tid >> 1, half = tid & 1;   // A-staging: 2 threads/row

  for (int it = 0; it < (N1q / Z2) / 32; ++it) {
    const int kt = z * (N1q / Z2) + it * 32;
    __syncthreads();
    // B tiles: async global->LDS
    #pragma unroll
    for (int t = 0; t < 2; ++t) {
      const int r  = rs0 + t * 16;
      const int cs = cl ^ ((r >> 1) & 3);
      GLD16(BT + (size_t)(n0 + r) * N1q + kt + cs * 8, Bs + (w * 32 + t * 16) * 32);
    }
    // A tiles: sum 2 fp16 partials + b1 -> fp16, swizzled ds_write
    {
      const _Float16* p = C1 + (size_t)(m0 + r2) * N1q + kt + half * 16;
      f16x8 u0 = *(const f16x8*)p;
      f16x8 u1 = *(const f16x8*)(p + 8);
      f16x8 v0 = *(const f16x8*)(p + MN1);
      f16x8 v1 = *(const f16x8*)(p + MN1 + 8);
      const float* bb = b1 + kt + half * 16;
      f16x8 o0, o1;
      #pragma unroll
      for (int e = 0; e < 8; ++e) {
        o0[e] = (_Float16)((float)u0[e] + (float)v0[e] + bb[e]);
        o1[e] = (_Float16)((float)u1[e] + (float)v1[e] + bb[e + 8]);
      }
      const int s  = (r2 >> 1) & 3;
      *(f16x8*)(As + r2 * 32 + (((half * 2)     ^ s) << 3)) = o0;
      *(f16x8*)(As + r2 * 32 + (((half * 2 + 1) ^ s) << 3)) = o1;
    }
    __syncthreads();
    f16x8 af[4], bf[4];
    #pragma unroll
    for (int i = 0; i < 4; ++i) {
      const int ar = wm + i * 16 + ml;
      af[i] = *(const f16x8*)(As + ar * 32 + ((g4 ^ ((ar >> 1) & 3)) << 3));
      const int br = wn + i * 16 + ml;
      bf[i] = *(const f16x8*)(Bs + br * 32 + ((g4 ^ ((br >> 1) & 3)) << 3));
    }
    #pragma unroll
    for (int i = 0; i < 4; ++i)
      #pragma unroll
      for (int j = 0; j < 4; ++j)
        acc[i][j] = __builtin_amdgcn_mfma_f32_16x16x32_f16(bf[j], af[i], acc[i][j], 0, 0, 0);
  }

  float* Cp = Cpart + (size_t)z * Mq * N2q;
  #pragma unroll
  for (int i = 0; i < 4; ++i) {
    const int row = m0 + wm + i * 16 + ml;
    #pragma unroll
    for (int j = 0; j < 4; ++j) {
      const int col = n0 + wn + j * 16 + g4 * 4;
      *(float4*)(Cp + (size_t)row * N2q + col) = *(const float4*)&acc[i][j];
    }
  }
}

// ---------- GEMM3 + fused loss, atomic-free: one 5-float partial per block
__global__ __launch_bounds__(256)
void loss_kernel(const float* __restrict__ C2, const float* __restrict__ b2,
                 const float* __restrict__ W3, const float* __restrict__ b3,
                 const float* __restrict__ labels, float* __restrict__ part) {
  __shared__ float hrow[4][512];
  __shared__ float red[4][5];
  const int tid = threadIdx.x, w = tid >> 6, lane = tid & 63;
  const int m = blockIdx.x * 4 + w;
  const size_t MN2 = (size_t)Mq * N2q;

  {
    const int k = lane * 8;
    float4 s0 = *(const float4*)(b2 + k);
    float4 s1 = *(const float4*)(b2 + k + 4);
    const float* cp = C2 + (size_t)m * N2q + k;
    #pragma unroll
    for (int z = 0; z < Z2; ++z) {
      float4 v0 = *(const float4*)(cp + (size_t)z * MN2);
      float4 v1 = *(const float4*)(cp + (size_t)z * MN2 + 4);
      s0.x += v0.x; s0.y += v0.y; s0.z += v0.z; s0.w += v0.w;
      s1.x += v1.x; s1.y += v1.y; s1.z += v1.z; s1.w += v1.w;
    }
    *(float4*)&hrow[w][k]     = s0;
    *(float4*)&hrow[w][k + 4] = s1;
  }
  __syncthreads();

  const int c  = lane & 31;
  const int kh = lane >> 5;
  float a0 = 0.f, a1 = 0.f, a2 = 0.f, a3 = 0.f;
  if (c < Lq) {
    const float* hp = hrow[w] + kh * 256;
    const float* wp = W3 + (size_t)(kh * 256) * Lq + c;
    #pragma unroll 4
    for (int i = 0; i < 256; i += 4) {
      a0 = fmaf(hp[i],     wp[(i)     * Lq], a0);
      a1 = fmaf(hp[i + 1], wp[(i + 1) * Lq], a1);
      a2 = fmaf(hp[i + 2], wp[(i + 2) * Lq], a2);
      a3 = fmaf(hp[i + 3], wp[(i + 3) * Lq], a3);
    }
  }
  float a = (a0 + a1) + (a2 + a3);
  a += __shfl_xor(a, 32);

  const bool act = lane < Lq;
  float logit = 0.f, lab = 0.f;
  if (act) {
    logit = a + b3[lane];
    lab = labels[(size_t)m * Lq + lane];
  }

  const unsigned long long validmask = __ballot(act && lab != -1.0f);
  const unsigned long long outmask   = __ballot(act && logit > 0.0f);
  const unsigned long long labmask   = __ballot(act && lab == 1.0f);
  const bool valid = (validmask != 0ULL);
  const int count_out = __popcll(outmask);
  const int count_lab = __popcll(labmask);

  float bce = 0.f;
  if (act && valid) {
    const float x = logit;
    bce = fmaxf(x, 0.f) + log1pf(expf(-fabsf(x))) - x * lab;
  }
  bce += __shfl_xor(bce, 16); bce += __shfl_xor(bce, 8);
  bce += __shfl_xor(bce, 4);  bce += __shfl_xor(bce, 2);
  bce += __shfl_xor(bce, 1);

  if (lane == 0) {
    float pb = 0.f, pv = 0.f, pc = 0.f, pe = 0.f, pp = 0.f;
    if (valid) {
      pb = bce; pv = 1.f;
      const float d = (float)count_out - (float)count_lab;
      pc = d * d;
    }
    if (count_out == 1 && count_lab == 1) {
      const float po = (float)(__ffsll((long long)outmask) - 1);
      const float pl = (float)(__ffsll((long long)labmask) - 1);
      pe = 1.f;
      const float dp = po - pl;
      pp = dp * dp;
    }
    red[w][0] = pb; red[w][1] = pv; red[w][2] = pc; red[w][3] = pe; red[w][4] = pp;
  }
  __syncthreads();
  if (tid < 5) {
    part[blockIdx.x * 5 + tid] =
        red[0][tid] + red[1][tid] + red[2][tid] + red[3][tid];
  }
}

// ---------- finalize: sum NBLK 5-float partials -> scalar loss
__global__ __launch_bounds__(256)
void finalize_kernel(const float* __restrict__ part, float* __restrict__ out) {
  __shared__ float red[32][5];
  const int t = threadIdx.x;
  if (t < 160) {
    const int j = t % 5, grp = t / 5;
    float s = 0.f;
    for (int i = grp; i < NBLK; i += 32) s += part[i * 5 + j];
    red[grp][j] = s;
  }
  __syncthreads();
  if (t == 0) {
    float t0 = 0.f, t1 = 0.f, t2 = 0.f, t3 = 0.f, t4 = 0.f;
    #pragma unroll
    for (int g = 0; g < 32; ++g) {
      t0 += red[g][0]; t1 += red[g][1]; t2 += red[g][2];
      t3 += red[g][3]; t4 += red[g][4];
    }
    const float bce = t0 / (t1 * (float)Lq);
    const float cnt = 10.0f * t2 / (float)Mq;
    const float pos = (t3 > 0.f) ? 5.0f * t4 / fmaxf(t3, 1.0f) : 0.f;
    out[0] = bce + cnt + pos;
  }
}

extern "C" void kernel_launch(void* const* d_in, const int* in_sizes, int n_in,
                              void* d_out, int out_size, void* d_ws, size_t ws_size,
                              hipStream_t stream) {
  const float* tok    = (const float*)d_in[0];
  const float* pool   = (const float*)d_in[1];
  const int*   npos   = (const int*)  d_in[2];
  const float* labels = (const float*)d_in[3];
  const float* W1     = (const float*)d_in[4];
  const float* b1     = (const float*)d_in[5];
  const float* W2     = (const float*)d_in[6];
  const float* b2     = (const float*)d_in[7];
  const float* W3     = (const float*)d_in[8];
  const float* b3     = (const float*)d_in[9];
  float* out = (float*)d_out;

  char* ws = (char*)d_ws;
  _Float16* A1   = (_Float16*)(ws + 0x00000000);  // 6 MB  [2048][1536]
  _Float16* C1p  = (_Float16*)(ws + 0x00600000);  // 8 MB  [2][2048][1024] fp16
  _Float16* W1T  = (_Float16*)(ws + 0x00E00000);  // 3 MB  [1024][1536]
  _Float16* W2T  = (_Float16*)(ws + 0x01100000);  // 1 MB  [512][1024]
  float*    C2p  = (float*)   (ws + 0x01200000);  // 16 MB [4][2048][512]
  float*    part = (float*)   (ws + 0x02200000);  // 10 KB [512][5]

  prep_all<<<768, 256, 0, stream>>>(tok, pool, npos, W1, W2, A1, W1T, W2T);
  gemm1_f16<<<dim3(8, 16, Z1), 256, 0, stream>>>(A1, W1T, C1p);
  gemm2_fused<<<dim3(4, 16, Z2), 256, 0, stream>>>(C1p, b1, W2T, C2p);
  loss_kernel<<<NBLK, 256, 0, stream>>>(C2p, b2, W3, b3, labels, part);
  finalize_kernel<<<1, 256, 0, stream>>>(part, out);
}